// Round 10
// baseline (107.895 us; speedup 1.0000x reference)
//
#include <hip/hip_runtime.h>
#include <hip/hip_fp16.h>
#include <cstdint>
#include <cstddef>

// Problem constants: B=8, T=4096, D=512, H=512
constexpr int Bb = 8, Tt = 4096, Dd = 512, Hh = 512;
constexpr int Mm = Bb * Tt;          // 32768 rows
constexpr int CHUNKS = 128;
constexpr int CLEN = Tt / CHUNKS;    // 32

typedef short short8 __attribute__((ext_vector_type(8)));
typedef float f32x4 __attribute__((ext_vector_type(4)));

#define BMT 256   // time-rows per block
#define BHT 128   // h-cols per block
#define BKT 64
#define NIT 8     // K iterations

__device__ inline void gload_lds16(const void* g, void* lds) {
  __builtin_amdgcn_global_load_lds(
      (const __attribute__((address_space(1))) unsigned int*)g,
      (__attribute__((address_space(3))) unsigned int*)lds,
      16, 0, 0);
}

__device__ inline unsigned short bf16_rne(float f) {
  unsigned int u = __float_as_uint(f);
  unsigned int r = (u + 0x7FFFu + ((u >> 16) & 1u)) >> 16;
  return (unsigned short)r;
}

__device__ inline uint2 pack4_bf16(const float* p) {
  uint2 hv;
  hv.x = (unsigned)bf16_rne(p[0]) | ((unsigned)bf16_rne(p[1]) << 16);
  hv.y = (unsigned)bf16_rne(p[2]) | ((unsigned)bf16_rne(p[3]) << 16);
  return hv;
}

// Merged prep: blocks [0,16384) convert x -> xb; blocks [16384,16896) W -> Wc.
__global__ __launch_bounds__(256) void prep_all(
    const float* __restrict__ x, const float* __restrict__ Wz,
    const float* __restrict__ Wh, unsigned short* __restrict__ xb,
    unsigned short* __restrict__ Wc) {
  int bid = blockIdx.x;
  if (bid < 16384) {
    size_t i = (size_t)bid * 256 + threadIdx.x;
    float4 w = *(const float4*)(x + i * 4);
    *(uint2*)(xb + i * 4) = pack4_bf16((const float*)&w);
  } else {
    int j = (bid - 16384) * 256 + threadIdx.x;
    const float* src = (j < 65536) ? (Wz + (size_t)j * 4)
                                   : (Wh + (size_t)(j - 65536) * 4);
    float4 w = *(const float4*)src;
    *(uint2*)(Wc + (size_t)j * 4) = pack4_bf16((const float*)&w);
  }
}

// W-only prep (fallback when ws too small for xb)
__global__ __launch_bounds__(256) void prep_w(
    const float* __restrict__ Wz, const float* __restrict__ Wh,
    unsigned short* __restrict__ Wc) {
  int j = blockIdx.x * 256 + threadIdx.x;
  const float* src = (j < 65536) ? (Wz + (size_t)j * 4)
                                 : (Wh + (size_t)(j - 65536) * 4);
  float4 w = *(const float4*)src;
  *(uint2*)(Wc + (size_t)j * 4) = pack4_bf16((const float*)&w);
}

// Fused dual-GEMM + gates + chunk-aggregates, counted-vmcnt double-buffered.
// Block: 256 rows x 128 h, 8 waves (wave = 64x64 dual-pipe), LDS 2 x 64KB.
// Per buffer: A[256x64] @0 (32KB), Bz[128x64] @16384 us, Bh @24576 us.
// T2 XOR swizzle: linear LDS dest + pre-swizzled global source (rule #21).
template <int XB>
__global__ __launch_bounds__(512, 2) void gemm_fused(
    const float* __restrict__ x, const unsigned short* __restrict__ xb,
    const unsigned short* __restrict__ Wc,
    const float* __restrict__ bz, const float* __restrict__ bh,
    unsigned int* __restrict__ av,
    float* __restrict__ aggA, float* __restrict__ aggH) {
  __shared__ __align__(16) char smem[131072];
  unsigned short* buf0 = (unsigned short*)smem;            // 64KB
  unsigned short* buf1 = (unsigned short*)(smem + 65536);  // 64KB
  float* AsL = (float*)smem;                               // [64][128] 32KB alias
  float* HsL = (float*)(smem + 32768);                     // [64][128] 32KB alias

  const int tid = threadIdx.x;
  const int lane = tid & 63, wid = tid >> 6;
  // XCD-aware bijective swizzle (512 % 8 == 0)
  int swz = (blockIdx.x & 7) * 64 + (blockIdx.x >> 3);
  const int bm = swz >> 2, hn = swz & 3;
  const int row0 = bm * BMT, h0 = hn * BHT;

  const int wr = (wid >> 1) * 64, hc = (wid & 1) * 64;  // wave sub-tile
  const int fr = lane & 15, kg = lane >> 4;

  // gload: wave covers 8 rows x 64 cols (1KB) per issue; pre-swizzled src slot
  const int r8 = lane >> 3;
  const int c8 = ((lane & 7) ^ r8) * 8;
  // fragment-read swizzled slots
  const int fr7 = lane & 7;
  const int sk0 = (kg ^ fr7) * 8;
  const int sk1 = ((kg + 4) ^ fr7) * 8;

  f32x4 ak[4][4], ap[4][4];
#pragma unroll
  for (int i = 0; i < 4; ++i)
#pragma unroll
    for (int j = 0; j < 4; ++j) { ak[i][j] = (f32x4)0.f; ap[i][j] = (f32x4)0.f; }

  // per-wave staging: A 4 issues (rows wid*32+i*8), Bz 2, Bh 2 -> 8 in flight
#define STAGE(T, BB)                                                           \
  {                                                                            \
    const int kk = (T) * BKT;                                                  \
    unsigned short* bb = (BB);                                                 \
    _Pragma("unroll")                                                          \
    for (int i = 0; i < 4; ++i) {                                              \
      int rw = wid * 32 + i * 8;                                               \
      gload_lds16(xb + (size_t)(row0 + rw + r8) * Dd + kk + c8, bb + rw * BKT);\
    }                                                                          \
    _Pragma("unroll")                                                          \
    for (int i = 0; i < 2; ++i) {                                              \
      int rw = wid * 16 + i * 8;                                               \
      gload_lds16(Wc + (size_t)(h0 + rw + r8) * Dd + kk + c8,                  \
                  bb + 16384 + rw * BKT);                                      \
      gload_lds16(Wc + (size_t)(512 + h0 + rw + r8) * Dd + kk + c8,            \
                  bb + 24576 + rw * BKT);                                      \
    }                                                                          \
  }

  if constexpr (XB) STAGE(0, buf0);

  for (int t = 0; t < NIT; ++t) {
    const unsigned short *Ab, *Bzb, *Bhb;
    if constexpr (XB) {
      unsigned short* cur = (t & 1) ? buf1 : buf0;
      unsigned short* nxt = (t & 1) ? buf0 : buf1;
      if (t < NIT - 1) {
        STAGE(t + 1, nxt);
        asm volatile("s_waitcnt vmcnt(8)" ::: "memory");
      } else {
        asm volatile("s_waitcnt vmcnt(0)" ::: "memory");
      }
      __builtin_amdgcn_s_barrier();
      Ab = cur; Bzb = cur + 16384; Bhb = cur + 24576;
    } else {
      const int kk = t * BKT;
      float4 avx[8];
#pragma unroll
      for (int i = 0; i < 8; ++i) {
        int f = i * 512 + tid;
        avx[i] = *(const float4*)(x + (size_t)(row0 + (f >> 4)) * Dd + kk + (f & 15) * 4);
      }
      __syncthreads();
#pragma unroll
      for (int i = 0; i < 2; ++i) {
        int rw = wid * 16 + i * 8;
        gload_lds16(Wc + (size_t)(h0 + rw + r8) * Dd + kk + c8, buf0 + 16384 + rw * BKT);
        gload_lds16(Wc + (size_t)(512 + h0 + rw + r8) * Dd + kk + c8, buf0 + 24576 + rw * BKT);
      }
#pragma unroll
      for (int i = 0; i < 8; ++i) {
        int f = i * 512 + tid;
        int r = f >> 4;
        uint2 hv = pack4_bf16((const float*)&avx[i]);
        int soff = ((((f & 15) >> 1) ^ (r & 7)) * 8) + (f & 1) * 4;
        *(uint2*)&buf0[r * BKT + soff] = hv;
      }
      __syncthreads();
      Ab = buf0; Bzb = buf0 + 16384; Bhb = buf0 + 24576;
    }

    __builtin_amdgcn_s_setprio(1);
#pragma unroll
    for (int ks = 0; ks < 2; ++ks) {
      const int sk = ks ? sk1 : sk0;
      short8 fa[4], fz[4], fh[4];
#pragma unroll
      for (int mi = 0; mi < 4; ++mi)
        fa[mi] = *(const short8*)&Ab[(wr + mi * 16 + fr) * BKT + sk];
#pragma unroll
      for (int ni = 0; ni < 4; ++ni) {
        fz[ni] = *(const short8*)&Bzb[(hc + ni * 16 + fr) * BKT + sk];
        fh[ni] = *(const short8*)&Bhb[(hc + ni * 16 + fr) * BKT + sk];
      }
#pragma unroll
      for (int mi = 0; mi < 4; ++mi)
#pragma unroll
        for (int ni = 0; ni < 4; ++ni) {
          ak[mi][ni] = __builtin_amdgcn_mfma_f32_16x16x32_bf16(fa[mi], fz[ni], ak[mi][ni], 0, 0, 0);
          ap[mi][ni] = __builtin_amdgcn_mfma_f32_16x16x32_bf16(fa[mi], fh[ni], ap[mi][ni], 0, 0, 0);
        }
    }
    __builtin_amdgcn_s_setprio(0);
    if constexpr (XB) __builtin_amdgcn_s_barrier();  // reads done before overwrite
  }
#undef STAGE

  // ---- Fused epilogue ----
  __syncthreads();   // staging reads complete; smem reusable for As/Hs

  // C/D layout: col=lane&15 (fr), row=(lane>>4)*4+j (kg,j)
#pragma unroll
  for (int ni = 0; ni < 4; ++ni) {
    int colG = h0 + hc + ni * 16 + fr;
    float bzv = bz[colG];
    float bhv = bh[colG];
    int cl = hc + ni * 16 + fr;
#pragma unroll
    for (int mi = 0; mi < 4; ++mi) {
      float A4 = 1.f, H4 = 0.f;
#pragma unroll
      for (int j = 0; j < 4; ++j) {
        float kv = ak[mi][ni][j] + bzv;
        float pv = ap[mi][ni][j] + bhv;
        float a = 1.f / (1.f + __expf(kv));           // sigmoid(-k)
        float z = 1.f - a;
        float g = (pv >= 0.f) ? (pv + 0.5f) : 1.f / (1.f + __expf(-pv));
        float v = z * g;
        int row = row0 + wr + mi * 16 + kg * 4 + j;
        unsigned int u = (unsigned int)__half_as_ushort(__float2half_rn(a)) |
                         ((unsigned int)__half_as_ushort(__float2half_rn(v)) << 16);
        av[(size_t)row * Hh + colG] = u;
        H4 = fmaf(a, H4, v);     // 4-row segment scan
        A4 *= a;
      }
      int srow = (wr >> 2) + mi * 4 + kg;   // 0..63
      AsL[srow * BHT + cl] = A4;
      HsL[srow * BHT + cl] = H4;
    }
  }
  __syncthreads();

  // fold 8 segments -> 1 chunk (32 rows); 8 chunks x 128 cols = 1024 outputs
  const int b = row0 >> 12;
  const int cbase = (row0 & 4095) >> 5;
#pragma unroll
  for (int p0 = 0; p0 < 2; ++p0) {
    int p = p0 * 512 + tid;
    int chunk = p >> 7, cl = p & 127;
    float A = 1.f, H = 0.f;
#pragma unroll
    for (int s = 0; s < 8; ++s) {
      int srow = chunk * 8 + s;
      float As = AsL[srow * BHT + cl];
      float Hs = HsL[srow * BHT + cl];
      H = fmaf(As, H, Hs);
      A *= As;
    }
    size_t idx = ((size_t)b * CHUNKS + cbase + chunk) * Hh + h0 + cl;
    aggA[idx] = A;
    aggH[idx] = H;
  }
}

// Kogge-Stone scan over chunk aggregates (affine composition).
__global__ __launch_bounds__(256) void scan_carry_ks(
    const float* __restrict__ aggA, const float* __restrict__ aggH,
    const float* __restrict__ h0, float* __restrict__ carry) {
  __shared__ float As[256], Hs[256];
  const int tid = threadIdx.x;
  const int c = tid & 127;
  const int gch = blockIdx.x * 2 + (tid >> 7);   // 0..B*H-1
  const int b = gch >> 9, h = gch & 511;
  size_t base = (size_t)b * CHUNKS * Hh + h;
  float A = aggA[base + (size_t)c * Hh];
  float H = aggH[base + (size_t)c * Hh];
  As[tid] = A; Hs[tid] = H;
  __syncthreads();
#pragma unroll
  for (int s = 1; s < 128; s <<= 1) {
    float Al = 1.f, Hl = 0.f;
    const bool act = (c >= s);
    if (act) { Al = As[tid - s]; Hl = Hs[tid - s]; }
    __syncthreads();
    if (act) {
      H = fmaf(A, Hl, H);
      A = A * Al;
      As[tid] = A; Hs[tid] = H;
    }
    __syncthreads();
  }
  float hv = h0[(size_t)b * Hh + h];
  float g0 = (hv >= 0.f) ? (hv + 0.5f) : 1.f / (1.f + __expf(-hv));  // g(h0)
  float cr;
  if (c == 0) cr = g0;
  else cr = fmaf(As[tid - 1], g0, Hs[tid - 1]);
  carry[base + (size_t)c * Hh] = cr;
}

// Apply carry: read packed (a,v), write final h (fp32) to d_out.
__global__ __launch_bounds__(512) void scan_apply_av(
    const unsigned int* __restrict__ av, const float* __restrict__ carry,
    float* __restrict__ out) {
  const int h = threadIdx.x;
  const int bc = blockIdx.x;
  const int b = bc >> 7, c = bc & 127;
  float hp = carry[(size_t)bc * Hh + h];
  size_t base = ((size_t)b * Tt + (size_t)c * CLEN) * Hh + h;
#pragma unroll
  for (int i = 0; i < CLEN; ++i) {
    size_t idx = base + (size_t)i * Hh;
    unsigned int u = av[idx];
    float a = __half2float(__ushort_as_half((unsigned short)(u & 0xFFFFu)));
    float v = __half2float(__ushort_as_half((unsigned short)(u >> 16)));
    hp = fmaf(a, hp, v);
    out[idx] = hp;
  }
}

extern "C" void kernel_launch(void* const* d_in, const int* in_sizes, int n_in,
                              void* d_out, int out_size, void* d_ws, size_t ws_size,
                              hipStream_t stream) {
  const float* x  = (const float*)d_in[0];
  const float* h0 = (const float*)d_in[1];
  const float* Wz = (const float*)d_in[2];
  const float* bz = (const float*)d_in[3];
  const float* Wh = (const float*)d_in[4];
  const float* bh = (const float*)d_in[5];
  float* out = (float*)d_out;

  char* w = (char*)d_ws;
  unsigned int* avb    = (unsigned int*)w;                 // 64 MB packed (a,v)
  unsigned short* Wc   = (unsigned short*)(w + 67108864);  // 1 MB
  float* aggA          = (float*)(w + 68157440);           // 2 MB
  float* aggH          = (float*)(w + 70254592);           // 2 MB
  float* carry         = (float*)(w + 72351744);           // 2 MB (end 74448896)
  unsigned short* xb   = (unsigned short*)(w + 74448896);  // 32 MB (end 108003328)
  const bool useXB = ws_size >= 108003328ull;

  const int grid = (Mm / BMT) * (Hh / BHT);  // 128 * 4 = 512
  if (useXB) {
    prep_all<<<16896, 256, 0, stream>>>(x, Wz, Wh, xb, Wc);
    gemm_fused<1><<<grid, 512, 0, stream>>>(x, xb, Wc, bz, bh, avb, aggA, aggH);
  } else {
    prep_w<<<512, 256, 0, stream>>>(Wz, Wh, Wc);
    gemm_fused<0><<<grid, 512, 0, stream>>>(x, xb, Wc, bz, bh, avb, aggA, aggH);
  }
  scan_carry_ks<<<(Bb * Hh) / 2, 256, 0, stream>>>(aggA, aggH, h0, carry);
  scan_apply_av<<<Bb * CHUNKS, 512, 0, stream>>>(avb, carry, out);
}